// Round 16
// baseline (298.443 us; speedup 1.0000x reference)
//
#include <hip/hip_runtime.h>
#include <stdint.h>

#define BB 16
#define HH 512
#define WW 512
#define HW 262144            // 2^18
#define BHW 4194304          // 16 * 2^18
#define KSEL 262
#define CHK 16384            // phase-A chunk (16 per batch)
#define CSTRIDE 288          // per-chunk slots in cand (262 used + zero pad)
#define CBATCH (16 * CSTRIDE) // 4608 = 512*9 entries per batch

// ---------- helpers (rn intrinsics to suppress fma contraction in selection-critical math) ----------
__device__ __forceinline__ float img01(float xv) {
    return __fmul_rn(__fadd_rn(xv, 1.0f), 0.5f);
}
__device__ __forceinline__ float luma3(float c0, float c1, float c2) {
    float t = __fadd_rn(__fmul_rn(0.2989f, c0), __fmul_rn(0.587f, c1));
    return __fadd_rn(t, __fmul_rn(0.114f, c2));
}

// ---------- radix-16 exact k-th-largest select over register-resident values ----------
// NW waves. Counts packed 4 bins/u64 in 16-bit lanes (block totals <= 16384 < 65536).
// Returns v (bit pattern of K-th largest; uint order == value order for floats >= 0)
// and r (ties of v to include by ascending index). Same recurrence as proven radix-256.
template <int ELT, int NW>
__device__ __forceinline__ void radix16_select(const uint32_t (&v)[ELT],
                                               unsigned long long* wsum, int t, int lane, int wv,
                                               uint32_t K, uint32_t& pref_out, uint32_t& r_out) {
    uint32_t pref = 0, target = K;
    for (int step = 0; step < 8; ++step) {
        int shift = 28 - 4 * step;
        uint32_t maskhi = step ? (0xFFFFFFFFu << (shift + 4)) : 0u;
        unsigned long long p0 = 0, p1 = 0, p2 = 0, p3 = 0;
        #pragma unroll
        for (int e = 0; e < ELT; ++e) {
            uint32_t u = v[e];
            bool ok = ((u & maskhi) == pref);
            uint32_t d = (u >> shift) & 15u;
            unsigned long long inc = ok ? (1ULL << ((d & 3u) * 16u)) : 0ULL;
            uint32_t q = d >> 2;
            p0 += (q == 0) ? inc : 0;
            p1 += (q == 1) ? inc : 0;
            p2 += (q == 2) ? inc : 0;
            p3 += (q == 3) ? inc : 0;
        }
        #pragma unroll
        for (int off = 32; off > 0; off >>= 1) {
            p0 += __shfl_down(p0, off, 64);
            p1 += __shfl_down(p1, off, 64);
            p2 += __shfl_down(p2, off, 64);
            p3 += __shfl_down(p3, off, 64);
        }
        if (lane == 0) {
            wsum[wv * 4 + 0] = p0; wsum[wv * 4 + 1] = p1;
            wsum[wv * 4 + 2] = p2; wsum[wv * 4 + 3] = p3;
        }
        __syncthreads();
        unsigned long long s0 = 0, s1 = 0, s2 = 0, s3 = 0;
        #pragma unroll
        for (int w = 0; w < NW; ++w) {
            s0 += wsum[w * 4 + 0]; s1 += wsum[w * 4 + 1];
            s2 += wsum[w * 4 + 2]; s3 += wsum[w * 4 + 3];
        }
        __syncthreads();
        uint32_t cum = 0, digit = 0, tgt = target;
        for (int d2 = 15; d2 >= 0; --d2) {
            unsigned long long ps = (d2 < 4) ? s0 : (d2 < 8) ? s1 : (d2 < 12) ? s2 : s3;
            uint32_t c2 = (uint32_t)((ps >> ((d2 & 3) * 16)) & 0xFFFFu);
            if (cum + c2 >= tgt) { digit = (uint32_t)d2; tgt -= cum; break; }
            cum += c2;
        }
        pref |= digit << shift;
        target = tgt;
    }
    pref_out = pref;
    r_out = target;
}

// ============ dark channel row pass (fused prep + cand zero-init) ============
__global__ void k_dc_row(const float* __restrict__ x, float* __restrict__ Ib, float* __restrict__ rm,
                         uint2* __restrict__ cand) {
    int bid = blockIdx.x;              // 16*512
    int b = bid >> 9, y = bid & 511;
    int t = threadIdx.x;
    if (bid < 16) {                    // zero one batch's cand region (incl. pads)
        unsigned long long* cz = (unsigned long long*)(cand + (size_t)bid * CBATCH);
        #pragma unroll
        for (int i = 0; i < 18; ++i) cz[i * 256 + t] = 0ull;   // 18*256 = 4608
    }
    __shared__ float lcm[528];         // logical [-8, 519], offset 8, pad = 1.0
    const float* xb = x + (size_t)b * 3 * HW + (size_t)y * WW;
    size_t obase = (size_t)b * HW + (size_t)y * WW;
    for (int xx = t; xx < 512; xx += 256) {
        float x0 = xb[xx], x1 = xb[HW + xx], x2 = xb[2 * HW + xx];
        float i0 = img01(x0), i1 = img01(x1), i2 = img01(x2);
        lcm[8 + xx] = fminf(i0, fminf(i1, i2));
        float tt = luma3(x0, x1, x2);
        Ib[obase + xx] = __fmul_rn(__fadd_rn(tt, 1.0f), 0.5f);
    }
    if (t < 16) lcm[(t < 8) ? t : (512 + t)] = 1.0f;
    __syncthreads();
    for (int xx = t; xx < 512; xx += 256) {
        float m = lcm[8 + xx - 7];
        #pragma unroll
        for (int k = -6; k <= 7; ++k) m = fminf(m, lcm[8 + xx + k]);
        rm[obase + xx] = m;
    }
}

// ============ col min pass (dark channel only): rm -> dc ============
__global__ void k_dc_col0(const float* __restrict__ in, float* __restrict__ out) {
    // grid 16*4*8; tile 128 cols x (64+14) rows
    int bid = blockIdx.x;
    int b = bid >> 5, cg = (bid >> 3) & 3, seg = bid & 7;
    int c0 = cg * 128, y0 = seg * 64;
    int t = threadIdx.x;
    __shared__ float tile[78 * 128];
    const float* ib = in + (size_t)b * HW;
    for (int i = t; i < 78 * 128; i += 256) {
        int rr = i >> 7, cc = i & 127;
        int gy = y0 - 7 + rr;
        tile[i] = (gy >= 0 && gy < 512) ? ib[(size_t)gy * WW + c0 + cc] : 1.0f;
    }
    __syncthreads();
    int col = t & 127;
    int rbase = (t >> 7) * 32;
    size_t obase = (size_t)b * HW + c0 + col;
    for (int rr = rbase; rr < rbase + 32; ++rr) {
        float m = tile[rr * 128 + col];
        #pragma unroll
        for (int k = 1; k < 15; ++k) m = fminf(m, tile[(rr + k) * 128 + col]);
        out[obase + (size_t)(y0 + rr) * WW] = m;
    }
}

// ============ phase A: per-chunk (16384) exact local top-262, registers, full-chip grid ============
// Thread t owns elements [t*64, t*64+64) ascending-contiguous; compaction emits canonical
// order: strict-greater (ascending idx) then first-r ties (ascending idx) — exactly 262.
__global__ __launch_bounds__(256, 1) void k_topkA(const float* __restrict__ dc, uint2* __restrict__ cand) {
    int b = blockIdx.x >> 4, blk = blockIdx.x & 15;   // grid 256
    int t = threadIdx.x, lane = t & 63, wv = t >> 6;
    __shared__ unsigned long long wsum[16];
    __shared__ uint32_t woffs[4];
    uint32_t v[64];
    const uint4* d4 = (const uint4*)(dc + (size_t)b * HW + (size_t)blk * CHK);
    #pragma unroll
    for (int it = 0; it < 16; ++it) {
        uint4 q = d4[t * 16 + it];
        v[it * 4 + 0] = q.x; v[it * 4 + 1] = q.y; v[it * 4 + 2] = q.z; v[it * 4 + 3] = q.w;
    }
    uint32_t pref, target;
    radix16_select<64, 4>(v, wsum, t, lane, wv, KSEL, pref, target);
    uint32_t cg = 0, ct = 0;
    #pragma unroll
    for (int e = 0; e < 64; ++e) {
        cg += (v[e] > pref) ? 1u : 0u;
        ct += (v[e] == pref) ? 1u : 0u;
    }
    uint32_t packed = (cg << 16) | ct;
    uint32_t scan = packed;
    #pragma unroll
    for (int off = 1; off < 64; off <<= 1) {
        uint32_t n = __shfl_up(scan, off, 64);
        if (lane >= off) scan += n;
    }
    if (lane == 63) woffs[wv] = scan;
    __syncthreads();
    uint32_t woff = 0;
    #pragma unroll
    for (int w = 0; w < 4; ++w) woff += (w < wv) ? woffs[w] : 0u;
    uint32_t total = woffs[0] + woffs[1] + woffs[2] + woffs[3];
    uint32_t G = total >> 16;            // strict-greater count (<= 261)
    uint32_t excl = woff + scan - packed;
    uint32_t gpos = excl >> 16, tpos = excl & 0xFFFFu;
    uint2* cb = cand + (size_t)(b * 16 + blk) * CSTRIDE;
    #pragma unroll
    for (int e = 0; e < 64; ++e) {
        uint32_t u = v[e];
        uint32_t idx = (uint32_t)(blk * CHK + t * 64 + e);
        if (u > pref) { cb[gpos] = make_uint2(u, idx); ++gpos; }
        else if (u == pref) { if (tpos < target) cb[G + tpos] = make_uint2(u, idx); ++tpos; }
    }
}

// ============ fused: A-selection prologue + cmin2/row-min (30 rows, batch-staged LDS) +
//              col-min(15) -> trans_raw -> GF row sums {I,p,Ip,II} ============
// grid 16*32, 512 threads (8 waves). v2: all 30 cmin rows staged into LDS at once
// (2 barriers instead of 60); division replaced by reciprocal-multiply (continuous path,
// error ~1e-7 << threshold); GF phase stages 16-row LI/LP panels into the SAME LDS
// (dead after rv extraction) -> barrier-free sum loop. ~5 barriers total (was ~92).
__global__ __launch_bounds__(512) void k_dc2trans(const float* __restrict__ x,
                                                  const uint2* __restrict__ cand,
                                                  const float* __restrict__ Ib,
                                                  float* __restrict__ rs, float* __restrict__ mapA3) {
    int bid = blockIdx.x;              // 16*32
    int b = bid >> 5, seg = bid & 31;
    int t = threadIdx.x, lane = t & 63, wv = t >> 6;   // 8 waves
    __shared__ unsigned long long wsum[32];
    __shared__ uint32_t woffs[8];
    __shared__ unsigned long long redg[8], redt[8];
    __shared__ float sInv[3];
    __shared__ float S[2 * 16 * 544];  // 69.6 KB union: LCM[30][528] then LI[16][544]+LP[16][544]
    float* LCM = S;                    // row j at S[j*528], logical col [-8,519] offset 8, pad 1.0
    float* LI = S;                     // row j at S[j*544], logical col [-16,527] offset 16, pad 0
    float* LP = S + 16 * 544;
    const uint2* cb = cand + (size_t)b * CBATCH;
    const float* xb = x + (size_t)b * 3 * HW;
    // ---- A-selection prologue (identical semantics to R14/R15) ----
    uint32_t v[9];
    #pragma unroll
    for (int e = 0; e < 9; ++e) v[e] = cb[t * 9 + e].x;
    uint32_t pref, target;
    radix16_select<9, 8>(v, wsum, t, lane, wv, KSEL, pref, target);
    unsigned long long bg = 0;
    uint32_t c = 0;
    #pragma unroll
    for (int e = 0; e < 9; ++e) {
        uint32_t u = v[e];
        if (u == pref) {
            ++c;
        } else if (u > pref) {
            uint32_t gidx = cb[t * 9 + e].y;
            float i0 = img01(xb[gidx]), i1 = img01(xb[HW + gidx]), i2 = img01(xb[2 * HW + gidx]);
            float inten = luma3(i0, i1, i2);
            unsigned long long pk =
                ((unsigned long long)__float_as_uint(inten) << 32) | (uint32_t)(0xFFFFFFFFu - gidx);
            if (pk > bg) bg = pk;
        }
    }
    uint32_t cs = c;
    #pragma unroll
    for (int off = 1; off < 64; off <<= 1) {
        uint32_t n = __shfl_up(cs, off, 64);
        if (lane >= off) cs += n;
    }
    if (lane == 63) woffs[wv] = cs;
    __syncthreads();
    uint32_t woff = 0;
    #pragma unroll
    for (int w = 0; w < 8; ++w) woff += (w < wv) ? woffs[w] : 0u;
    uint32_t pos = woff + cs - c;
    unsigned long long bt = 0;
    #pragma unroll
    for (int e = 0; e < 9; ++e) {
        if (v[e] == pref) {
            if (pos < target) {
                uint32_t gidx = cb[t * 9 + e].y;
                float i0 = img01(xb[gidx]), i1 = img01(xb[HW + gidx]), i2 = img01(xb[2 * HW + gidx]);
                float inten = luma3(i0, i1, i2);
                unsigned long long pk =
                    ((unsigned long long)__float_as_uint(inten) << 32) | (uint32_t)(0xFFFFFFFFu - gidx);
                if (pk > bt) bt = pk;
            }
            ++pos;
        }
    }
    #pragma unroll
    for (int off = 32; off > 0; off >>= 1) {
        unsigned long long og = __shfl_down(bg, off, 64);
        unsigned long long ot = __shfl_down(bt, off, 64);
        if (og > bg) bg = og;
        if (ot > bt) bt = ot;
    }
    if (lane == 0) { redg[wv] = bg; redt[wv] = bt; }
    __syncthreads();
    if (t == 0) {
        unsigned long long g = 0, tie = 0;
        #pragma unroll
        for (int w = 0; w < 8; ++w) {
            if (redg[w] > g) g = redg[w];
            if (redt[w] > tie) tie = redt[w];
        }
        unsigned long long fin = ((g >> 32) >= (tie >> 32)) ? g : tie;   // equal intensity -> gt wins
        if (g == 0ull) fin = tie;
        uint32_t rem = 0xFFFFFFFFu - (uint32_t)(fin & 0xFFFFFFFFull);
        for (int c2 = 0; c2 < 3; ++c2) {
            float A = img01(xb[(size_t)c2 * HW + rem]);
            float mA = __fsub_rn(__fmul_rn(A, 2.0f), 1.0f);
            float Ap = __fmul_rn(__fadd_rn(mA, 1.0f), 0.5f);
            sInv[c2] = 1.0f / Ap;
            if (seg == 0) mapA3[b * 3 + c2] = mA;
        }
    }
    // row pads for all 30 LCM rows (1.0)
    if (t < 480) {
        int j = t >> 4, s = t & 15;
        LCM[j * 528 + ((s < 8) ? s : (512 + s))] = 1.0f;
    }
    __syncthreads();
    float inv0 = sInv[0], inv1 = sInv[1], inv2 = sInv[2];
    int col = t;
    int y0 = seg * 16;
    // ---- stage all 30 cmin rows (no barriers inside) ----
    #pragma unroll
    for (int j = 0; j < 30; ++j) {
        int y = y0 - 7 + j;
        if (y >= 0 && y < 512) {   // uniform across block
            size_t ro = (size_t)y * WW + col;
            float v0 = __fmul_rn(img01(xb[ro]), inv0);
            float v1 = __fmul_rn(img01(xb[HW + ro]), inv1);
            float v2 = __fmul_rn(img01(xb[2 * HW + ro]), inv2);
            LCM[j * 528 + 8 + col] = fminf(v0, fminf(v1, v2));
        }
    }
    __syncthreads();
    // ---- row-min(15) per row -> rv (read-only, no barriers) ----
    float rv[30];
    #pragma unroll
    for (int j = 0; j < 30; ++j) {
        int y = y0 - 7 + j;
        if (y >= 0 && y < 512) {
            float m = LCM[j * 528 + 8 + col - 7];
            #pragma unroll
            for (int k = -6; k <= 7; ++k) m = fminf(m, LCM[j * 528 + 8 + col + k]);
            rv[j] = m;
        } else {
            rv[j] = 1e30f;
        }
    }
    // ---- col-min(15) -> trans_raw ----
    float pv[16];
    #pragma unroll
    for (int j = 0; j < 16; ++j) {
        float m = rv[j];
        #pragma unroll
        for (int k = 1; k < 15; ++k) m = fminf(m, rv[j + k]);
        int y = y0 + j;
        if (y < 7 || y > 504) m = fminf(m, 1.0f);   // window clipped -> pad 1.0 participates
        pv[j] = __fsub_rn(1.0f, __fmul_rn(0.95f, m));
    }
    __syncthreads();   // LCM dead; safe to overwrite with LI/LP
    // ---- stage LI (16 rows of Ib) + LP (pv) with zero pads; one pad slot per thread ----
    {
        int j2 = t >> 5, s2 = t & 31;
        int padidx = (s2 < 16) ? s2 : (512 + s2);
        LI[j2 * 544 + padidx] = 0.f;
        LP[j2 * 544 + padidx] = 0.f;
    }
    const float* ibp = Ib + (size_t)b * HW;
    #pragma unroll
    for (int j = 0; j < 16; ++j) {
        LI[j * 544 + 16 + col] = ibp[(size_t)(y0 + j) * WW + col];
        LP[j * 544 + 16 + col] = pv[j];
    }
    __syncthreads();
    // ---- GF row sums, barrier-free ----
    for (int j = 0; j < 16; ++j) {
        float sI = 0.f, sP = 0.f, sIP = 0.f, sII = 0.f;
        #pragma unroll
        for (int k = -15; k <= 15; ++k) {
            float iv = LI[j * 544 + 16 + col + k];
            float pp = LP[j * 544 + 16 + col + k];
            sI += iv; sP += pp; sIP += iv * pp; sII += iv * iv;
        }
        size_t o = (size_t)b * HW + (size_t)(y0 + j) * WW + col;
        rs[o] = sI;
        rs[(size_t)BHW + o] = sP;
        rs[(size_t)2 * BHW + o] = sIP;
        rs[(size_t)3 * BHW + o] = sII;
    }
}

// ============ fused: GF col running-sums -> a,b (LDS) -> row sums ra,rb ============
__global__ void k_colab_row2(const float* __restrict__ rs, float* __restrict__ ra,
                             float* __restrict__ rb) {
    int bid = blockIdx.x;              // 16*32
    int b = bid >> 5, seg = bid & 31;
    int y0 = seg * 16;
    int col = threadIdx.x;             // 512 threads
    __shared__ float La[544], Lb[544];
    const float* rI = rs;
    const float* rP = rs + (size_t)BHW;
    const float* rIP = rs + (size_t)2 * BHW;
    const float* rII = rs + (size_t)3 * BHW;
    size_t pc = (size_t)b * HW + col;
    float sI = 0.f, sP = 0.f, sIP = 0.f, sII = 0.f;
    for (int yy = y0 - 15; yy <= y0 + 15; ++yy) {
        if (yy >= 0 && yy < 512) {
            size_t o = pc + (size_t)yy * WW;
            sI += rI[o]; sP += rP[o]; sIP += rIP[o]; sII += rII[o];
        }
    }
    int nx = min(511, col + 15) - max(0, col - 15) + 1;
    if (col < 32) {
        int i = (col < 16) ? col : (512 + col);
        La[i] = 0.f; Lb[i] = 0.f;
    }
    for (int j = 0; j < 16; ++j) {
        int y = y0 + j;
        if (j > 0) {
            int ya = y + 15, yr = y - 16;
            if (ya < 512) {
                size_t o = pc + (size_t)ya * WW;
                sI += rI[o]; sP += rP[o]; sIP += rIP[o]; sII += rII[o];
            }
            if (yr >= 0) {
                size_t o = pc + (size_t)yr * WW;
                sI -= rI[o]; sP -= rP[o]; sIP -= rIP[o]; sII -= rII[o];
            }
        }
        int ny = min(511, y + 15) - max(0, y - 15) + 1;
        float N = (float)(ny * nx);
        float mI = sI / N, mP = sP / N, mIP = sIP / N, mII = sII / N;
        float cov = mIP - mI * mP;
        float var = mII - mI * mI;
        float a = cov / (var + 1e-3f);
        float bb = mP - a * mI;
        La[16 + col] = a;
        Lb[16 + col] = bb;
        __syncthreads();
        float sa = 0.f, sb = 0.f;
        #pragma unroll
        for (int k = -15; k <= 15; ++k) {
            sa += La[16 + col + k];
            sb += Lb[16 + col + k];
        }
        size_t o = pc + (size_t)y * WW;
        ra[o] = sa;
        rb[o] = sb;
        __syncthreads();
    }
}

// ============ final: running column sums of ra,rb -> T, J, mapA (16-row segments) ============
__global__ void k_final_col(const float* __restrict__ ra, const float* __restrict__ rb,
                            const float* __restrict__ Ib, const float* __restrict__ x,
                            const float* __restrict__ mapA3, float* __restrict__ out) {
    int bid = blockIdx.x;
    int b = bid >> 6, cg = (bid >> 5) & 1, seg = bid & 31;
    int col = cg * 256 + threadIdx.x;
    int y0 = seg * 16;
    size_t pc = (size_t)b * HW + col;
    float mA0 = mapA3[b * 3 + 0], mA1 = mapA3[b * 3 + 1], mA2 = mapA3[b * 3 + 2];
    const float* x0p = x + (size_t)b * 3 * HW + col;
    float Sa = 0.f, Sb = 0.f;
    for (int yy = y0 - 15; yy <= y0 + 15; ++yy) {
        if (yy >= 0 && yy < 512) {
            size_t o = pc + (size_t)yy * WW;
            Sa += ra[o]; Sb += rb[o];
        }
    }
    int nx = min(511, col + 15) - max(0, col - 15) + 1;
    for (int j = 0; j < 16; ++j) {
        int y = y0 + j;
        if (j > 0) {
            int ya = y + 15, yr = y - 16;
            if (ya < 512) {
                size_t o = pc + (size_t)ya * WW;
                Sa += ra[o]; Sb += rb[o];
            }
            if (yr >= 0) {
                size_t o = pc + (size_t)yr * WW;
                Sa -= ra[o]; Sb -= rb[o];
            }
        }
        int ny = min(511, y + 15) - max(0, y - 15) + 1;
        float N = (float)(ny * nx);
        float ma = Sa / N, mb = Sb / N;
        size_t yo = (size_t)y * WW;
        float Iv = Ib[pc + yo];
        float T = ma * Iv + mb;
        out[(size_t)3 * BHW + pc + yo] = T;
        float i0 = img01(x0p[yo]);
        float i1 = img01(x0p[(size_t)HW + yo]);
        float i2 = img01(x0p[(size_t)2 * HW + yo]);
        size_t j0 = (size_t)(b * 3) * HW + yo + col;
        out[j0] = (i0 - mA0) / T + mA0;
        out[j0 + HW] = (i1 - mA1) / T + mA1;
        out[j0 + 2 * HW] = (i2 - mA2) / T + mA2;
        out[(size_t)4 * BHW + j0] = mA0;
        out[(size_t)4 * BHW + j0 + HW] = mA1;
        out[(size_t)4 * BHW + j0 + 2 * HW] = mA2;
    }
}

extern "C" void kernel_launch(void* const* d_in, const int* in_sizes, int n_in,
                              void* d_out, int out_size, void* d_ws, size_t ws_size,
                              hipStream_t stream) {
    const float* x = (const float*)d_in[0];
    float* out = (float*)d_out;
    char* ws = (char*)d_ws;

    // ws planes
    float* Ib = (float*)ws;                    // guidance
    float* rm = Ib + (size_t)BHW;              // first-DC row-min; later ra
    float* dc = Ib + (size_t)2 * BHW;          // dark channel; later rb
    uint2* cand = (uint2*)(ws + (size_t)3 * BHW * 4);            // 16*4608 uint2 = 576 KB
    char* small = ws + (size_t)3 * BHW * 4 + (size_t)1024 * 1024;
    float* mapA3 = (float*)(small);
    // d_out reuse: rs planes 0..3 (consumed by colab_row2 before final writes)
    float* rs = out;
    float* ra = rm;
    float* rb = dc;

    // dark channel of imgPatch (bit-exact min path) + cand zero-init
    k_dc_row<<<16 * 512, 256, 0, stream>>>(x, Ib, rm, cand);
    k_dc_col0<<<16 * 4 * 8, 256, 0, stream>>>(rm, dc);

    // exact per-chunk top-262 (full-chip grid, register-resident)
    k_topkA<<<16 * 16, 256, 0, stream>>>(dc, cand);

    // fused: A-selection + cmin2/row-min (batch-staged LDS) + col-min -> trans_raw -> GF row sums
    k_dc2trans<<<16 * 32, 512, 0, stream>>>(x, cand, Ib, rs, mapA3);

    // GF col pass + a,b + row sums (fused), then final col pass + outputs
    k_colab_row2<<<16 * 32, 512, 0, stream>>>(rs, ra, rb);
    k_final_col<<<16 * 2 * 32, 256, 0, stream>>>(ra, rb, Ib, x, mapA3, out);
}

// Round 17
// 263.821 us; speedup vs baseline: 1.1312x; 1.1312x over previous
//
#include <hip/hip_runtime.h>
#include <stdint.h>

#define BB 16
#define HH 512
#define WW 512
#define HW 262144            // 2^18
#define BHW 4194304          // 16 * 2^18
#define KSEL 262
#define CHK 16384            // phase-A chunk (16 per batch)
#define CSTRIDE 288          // per-chunk slots in cand (262 used + zero pad)
#define CBATCH (16 * CSTRIDE) // 4608 = 512*9 entries per batch

// ---------- helpers (rn intrinsics to suppress fma contraction in selection-critical math) ----------
__device__ __forceinline__ float img01(float xv) {
    return __fmul_rn(__fadd_rn(xv, 1.0f), 0.5f);
}
__device__ __forceinline__ float luma3(float c0, float c1, float c2) {
    float t = __fadd_rn(__fmul_rn(0.2989f, c0), __fmul_rn(0.587f, c1));
    return __fadd_rn(t, __fmul_rn(0.114f, c2));
}

// ---------- radix-16 exact k-th-largest select over register-resident values ----------
template <int ELT, int NW>
__device__ __forceinline__ void radix16_select(const uint32_t (&v)[ELT],
                                               unsigned long long* wsum, int t, int lane, int wv,
                                               uint32_t K, uint32_t& pref_out, uint32_t& r_out) {
    uint32_t pref = 0, target = K;
    for (int step = 0; step < 8; ++step) {
        int shift = 28 - 4 * step;
        uint32_t maskhi = step ? (0xFFFFFFFFu << (shift + 4)) : 0u;
        unsigned long long p0 = 0, p1 = 0, p2 = 0, p3 = 0;
        #pragma unroll
        for (int e = 0; e < ELT; ++e) {
            uint32_t u = v[e];
            bool ok = ((u & maskhi) == pref);
            uint32_t d = (u >> shift) & 15u;
            unsigned long long inc = ok ? (1ULL << ((d & 3u) * 16u)) : 0ULL;
            uint32_t q = d >> 2;
            p0 += (q == 0) ? inc : 0;
            p1 += (q == 1) ? inc : 0;
            p2 += (q == 2) ? inc : 0;
            p3 += (q == 3) ? inc : 0;
        }
        #pragma unroll
        for (int off = 32; off > 0; off >>= 1) {
            p0 += __shfl_down(p0, off, 64);
            p1 += __shfl_down(p1, off, 64);
            p2 += __shfl_down(p2, off, 64);
            p3 += __shfl_down(p3, off, 64);
        }
        if (lane == 0) {
            wsum[wv * 4 + 0] = p0; wsum[wv * 4 + 1] = p1;
            wsum[wv * 4 + 2] = p2; wsum[wv * 4 + 3] = p3;
        }
        __syncthreads();
        unsigned long long s0 = 0, s1 = 0, s2 = 0, s3 = 0;
        #pragma unroll
        for (int w = 0; w < NW; ++w) {
            s0 += wsum[w * 4 + 0]; s1 += wsum[w * 4 + 1];
            s2 += wsum[w * 4 + 2]; s3 += wsum[w * 4 + 3];
        }
        __syncthreads();
        uint32_t cum = 0, digit = 0, tgt = target;
        for (int d2 = 15; d2 >= 0; --d2) {
            unsigned long long ps = (d2 < 4) ? s0 : (d2 < 8) ? s1 : (d2 < 12) ? s2 : s3;
            uint32_t c2 = (uint32_t)((ps >> ((d2 & 3) * 16)) & 0xFFFFu);
            if (cum + c2 >= tgt) { digit = (uint32_t)d2; tgt -= cum; break; }
            cum += c2;
        }
        pref |= digit << shift;
        target = tgt;
    }
    pref_out = pref;
    r_out = target;
}

// ============ dark channel row pass (fused prep + cand zero-init) ============
__global__ void k_dc_row(const float* __restrict__ x, float* __restrict__ Ib, float* __restrict__ rm,
                         uint2* __restrict__ cand) {
    int bid = blockIdx.x;              // 16*512
    int b = bid >> 9, y = bid & 511;
    int t = threadIdx.x;
    if (bid < 16) {                    // zero one batch's cand region (incl. pads)
        unsigned long long* cz = (unsigned long long*)(cand + (size_t)bid * CBATCH);
        #pragma unroll
        for (int i = 0; i < 18; ++i) cz[i * 256 + t] = 0ull;   // 18*256 = 4608
    }
    __shared__ float lcm[528];         // logical [-8, 519], offset 8, pad = 1.0
    const float* xb = x + (size_t)b * 3 * HW + (size_t)y * WW;
    size_t obase = (size_t)b * HW + (size_t)y * WW;
    for (int xx = t; xx < 512; xx += 256) {
        float x0 = xb[xx], x1 = xb[HW + xx], x2 = xb[2 * HW + xx];
        float i0 = img01(x0), i1 = img01(x1), i2 = img01(x2);
        lcm[8 + xx] = fminf(i0, fminf(i1, i2));
        float tt = luma3(x0, x1, x2);
        Ib[obase + xx] = __fmul_rn(__fadd_rn(tt, 1.0f), 0.5f);
    }
    if (t < 16) lcm[(t < 8) ? t : (512 + t)] = 1.0f;
    __syncthreads();
    for (int xx = t; xx < 512; xx += 256) {
        float m = lcm[8 + xx - 7];
        #pragma unroll
        for (int k = -6; k <= 7; ++k) m = fminf(m, lcm[8 + xx + k]);
        rm[obase + xx] = m;
    }
}

// ============ col min pass (dark channel only): rm -> dc ============
__global__ void k_dc_col0(const float* __restrict__ in, float* __restrict__ out) {
    // grid 16*4*8; tile 128 cols x (64+14) rows
    int bid = blockIdx.x;
    int b = bid >> 5, cg = (bid >> 3) & 3, seg = bid & 7;
    int c0 = cg * 128, y0 = seg * 64;
    int t = threadIdx.x;
    __shared__ float tile[78 * 128];
    const float* ib = in + (size_t)b * HW;
    for (int i = t; i < 78 * 128; i += 256) {
        int rr = i >> 7, cc = i & 127;
        int gy = y0 - 7 + rr;
        tile[i] = (gy >= 0 && gy < 512) ? ib[(size_t)gy * WW + c0 + cc] : 1.0f;
    }
    __syncthreads();
    int col = t & 127;
    int rbase = (t >> 7) * 32;
    size_t obase = (size_t)b * HW + c0 + col;
    for (int rr = rbase; rr < rbase + 32; ++rr) {
        float m = tile[rr * 128 + col];
        #pragma unroll
        for (int k = 1; k < 15; ++k) m = fminf(m, tile[(rr + k) * 128 + col]);
        out[obase + (size_t)(y0 + rr) * WW] = m;
    }
}

// ============ phase A: per-chunk (16384) exact local top-262, registers, full-chip grid ============
__global__ __launch_bounds__(256, 1) void k_topkA(const float* __restrict__ dc, uint2* __restrict__ cand) {
    int b = blockIdx.x >> 4, blk = blockIdx.x & 15;   // grid 256
    int t = threadIdx.x, lane = t & 63, wv = t >> 6;
    __shared__ unsigned long long wsum[16];
    __shared__ uint32_t woffs[4];
    uint32_t v[64];
    const uint4* d4 = (const uint4*)(dc + (size_t)b * HW + (size_t)blk * CHK);
    #pragma unroll
    for (int it = 0; it < 16; ++it) {
        uint4 q = d4[t * 16 + it];
        v[it * 4 + 0] = q.x; v[it * 4 + 1] = q.y; v[it * 4 + 2] = q.z; v[it * 4 + 3] = q.w;
    }
    uint32_t pref, target;
    radix16_select<64, 4>(v, wsum, t, lane, wv, KSEL, pref, target);
    uint32_t cg = 0, ct = 0;
    #pragma unroll
    for (int e = 0; e < 64; ++e) {
        cg += (v[e] > pref) ? 1u : 0u;
        ct += (v[e] == pref) ? 1u : 0u;
    }
    uint32_t packed = (cg << 16) | ct;
    uint32_t scan = packed;
    #pragma unroll
    for (int off = 1; off < 64; off <<= 1) {
        uint32_t n = __shfl_up(scan, off, 64);
        if (lane >= off) scan += n;
    }
    if (lane == 63) woffs[wv] = scan;
    __syncthreads();
    uint32_t woff = 0;
    #pragma unroll
    for (int w = 0; w < 4; ++w) woff += (w < wv) ? woffs[w] : 0u;
    uint32_t total = woffs[0] + woffs[1] + woffs[2] + woffs[3];
    uint32_t G = total >> 16;            // strict-greater count (<= 261)
    uint32_t excl = woff + scan - packed;
    uint32_t gpos = excl >> 16, tpos = excl & 0xFFFFu;
    uint2* cb = cand + (size_t)(b * 16 + blk) * CSTRIDE;
    #pragma unroll
    for (int e = 0; e < 64; ++e) {
        uint32_t u = v[e];
        uint32_t idx = (uint32_t)(blk * CHK + t * 64 + e);
        if (u > pref) { cb[gpos] = make_uint2(u, idx); ++gpos; }
        else if (u == pref) { if (tpos < target) cb[G + tpos] = make_uint2(u, idx); ++tpos; }
    }
}

// ============ dc2 row pass with fused A-selection prologue (R14 structure + reciprocal) ============
__global__ __launch_bounds__(512) void k_dc2_row(const float* __restrict__ x,
                                                 const uint2* __restrict__ cand,
                                                 float* __restrict__ rm, float* __restrict__ mapA3) {
    int bid = blockIdx.x;              // 16*32
    int b = bid >> 5, seg = bid & 31;
    int t = threadIdx.x, lane = t & 63, wv = t >> 6;   // 8 waves
    __shared__ unsigned long long wsum[32];
    __shared__ uint32_t woffs[8];
    __shared__ unsigned long long redg[8], redt[8];
    __shared__ float sInv[3];
    __shared__ float lcm[528];
    const uint2* cb = cand + (size_t)b * CBATCH;
    const float* xb = x + (size_t)b * 3 * HW;
    uint32_t v[9];
    #pragma unroll
    for (int e = 0; e < 9; ++e) v[e] = cb[t * 9 + e].x;
    uint32_t pref, target;
    radix16_select<9, 8>(v, wsum, t, lane, wv, KSEL, pref, target);
    unsigned long long bg = 0;
    uint32_t c = 0;
    #pragma unroll
    for (int e = 0; e < 9; ++e) {
        uint32_t u = v[e];
        if (u == pref) {
            ++c;
        } else if (u > pref) {
            uint32_t gidx = cb[t * 9 + e].y;
            float i0 = img01(xb[gidx]), i1 = img01(xb[HW + gidx]), i2 = img01(xb[2 * HW + gidx]);
            float inten = luma3(i0, i1, i2);
            unsigned long long pk =
                ((unsigned long long)__float_as_uint(inten) << 32) | (uint32_t)(0xFFFFFFFFu - gidx);
            if (pk > bg) bg = pk;
        }
    }
    uint32_t cs = c;
    #pragma unroll
    for (int off = 1; off < 64; off <<= 1) {
        uint32_t n = __shfl_up(cs, off, 64);
        if (lane >= off) cs += n;
    }
    if (lane == 63) woffs[wv] = cs;
    __syncthreads();
    uint32_t woff = 0;
    #pragma unroll
    for (int w = 0; w < 8; ++w) woff += (w < wv) ? woffs[w] : 0u;
    uint32_t pos = woff + cs - c;
    unsigned long long bt = 0;
    #pragma unroll
    for (int e = 0; e < 9; ++e) {
        if (v[e] == pref) {
            if (pos < target) {
                uint32_t gidx = cb[t * 9 + e].y;
                float i0 = img01(xb[gidx]), i1 = img01(xb[HW + gidx]), i2 = img01(xb[2 * HW + gidx]);
                float inten = luma3(i0, i1, i2);
                unsigned long long pk =
                    ((unsigned long long)__float_as_uint(inten) << 32) | (uint32_t)(0xFFFFFFFFu - gidx);
                if (pk > bt) bt = pk;
            }
            ++pos;
        }
    }
    #pragma unroll
    for (int off = 32; off > 0; off >>= 1) {
        unsigned long long og = __shfl_down(bg, off, 64);
        unsigned long long ot = __shfl_down(bt, off, 64);
        if (og > bg) bg = og;
        if (ot > bt) bt = ot;
    }
    if (lane == 0) { redg[wv] = bg; redt[wv] = bt; }
    __syncthreads();
    if (t == 0) {
        unsigned long long g = 0, tie = 0;
        #pragma unroll
        for (int w = 0; w < 8; ++w) {
            if (redg[w] > g) g = redg[w];
            if (redt[w] > tie) tie = redt[w];
        }
        unsigned long long fin = ((g >> 32) >= (tie >> 32)) ? g : tie;   // equal intensity -> gt wins
        if (g == 0ull) fin = tie;
        uint32_t rem = 0xFFFFFFFFu - (uint32_t)(fin & 0xFFFFFFFFull);
        for (int c2 = 0; c2 < 3; ++c2) {
            float A = img01(xb[(size_t)c2 * HW + rem]);
            float mA = __fsub_rn(__fmul_rn(A, 2.0f), 1.0f);
            float Ap = __fmul_rn(__fadd_rn(mA, 1.0f), 0.5f);
            sInv[c2] = 1.0f / Ap;
            if (seg == 0) mapA3[b * 3 + c2] = mA;
        }
    }
    if (t < 16) lcm[(t < 8) ? t : (512 + t)] = 1.0f;
    __syncthreads();
    float inv0 = sInv[0], inv1 = sInv[1], inv2 = sInv[2];
    int col = t;
    int y0 = seg * 16;
    for (int j = 0; j < 16; ++j) {
        size_t ro = (size_t)(y0 + j) * WW + col;
        float v0 = __fmul_rn(img01(xb[ro]), inv0);
        float v1 = __fmul_rn(img01(xb[HW + ro]), inv1);
        float v2 = __fmul_rn(img01(xb[2 * HW + ro]), inv2);
        lcm[8 + col] = fminf(v0, fminf(v1, v2));
        __syncthreads();
        float m = lcm[8 + col - 7];
        #pragma unroll
        for (int k = -6; k <= 7; ++k) m = fminf(m, lcm[8 + col + k]);
        rm[(size_t)b * HW + ro] = m;
        __syncthreads();
    }
}

// ============ fused: col-min(15) of rm -> trans_raw -> GF row sums (float4 AoS) ============
__global__ void k_trans_row1(const float* __restrict__ rm, const float* __restrict__ Ib,
                             float4* __restrict__ rs4) {
    int bid = blockIdx.x;              // 16*32
    int b = bid >> 5, seg = bid & 31;
    int y0 = seg * 16;
    int col = threadIdx.x;             // 512 threads, one per column
    __shared__ float LI[544], LP[544]; // logical [-16,527], offset 16, pad 0
    const float* rmp = rm + (size_t)b * HW;
    float rv[30];
    #pragma unroll
    for (int rix = 0; rix < 30; ++rix) {
        int gy = y0 - 7 + rix;
        rv[rix] = (gy >= 0 && gy < 512) ? rmp[(size_t)gy * WW + col] : 1e30f;
    }
    float pv[16];
    #pragma unroll
    for (int j = 0; j < 16; ++j) {
        float m = rv[j];
        #pragma unroll
        for (int k = 1; k < 15; ++k) m = fminf(m, rv[j + k]);
        int y = y0 + j;
        if (y < 7 || y > 504) m = fminf(m, 1.0f);   // window clipped -> pad 1.0 participates
        pv[j] = __fsub_rn(1.0f, __fmul_rn(0.95f, m));
    }
    if (col < 32) {
        int i = (col < 16) ? col : (512 + col);
        LI[i] = 0.f; LP[i] = 0.f;
    }
    const float* ibp = Ib + (size_t)b * HW;
    #pragma unroll
    for (int j = 0; j < 16; ++j) {
        int y = y0 + j;
        LI[16 + col] = ibp[(size_t)y * WW + col];
        LP[16 + col] = pv[j];
        __syncthreads();
        float sI = 0.f, sP = 0.f, sIP = 0.f, sII = 0.f;
        #pragma unroll
        for (int k = -15; k <= 15; ++k) {
            float iv = LI[16 + col + k], pp = LP[16 + col + k];
            sI += iv; sP += pp; sIP += iv * pp; sII += iv * iv;
        }
        rs4[(size_t)b * HW + (size_t)y * WW + col] = make_float4(sI, sP, sIP, sII);
        __syncthreads();
    }
}

// ============ fused: GF col running-sums (float4 AoS) -> a,b (LDS) -> row sums (float2 AoS) ============
__global__ void k_colab_row2(const float4* __restrict__ rs4, float2* __restrict__ rab) {
    int bid = blockIdx.x;              // 16*32
    int b = bid >> 5, seg = bid & 31;
    int y0 = seg * 16;
    int col = threadIdx.x;             // 512 threads
    __shared__ float La[544], Lb[544];
    size_t pc = (size_t)b * HW + col;
    float sI = 0.f, sP = 0.f, sIP = 0.f, sII = 0.f;
    for (int yy = y0 - 15; yy <= y0 + 15; ++yy) {
        if (yy >= 0 && yy < 512) {
            float4 q = rs4[pc + (size_t)yy * WW];
            sI += q.x; sP += q.y; sIP += q.z; sII += q.w;
        }
    }
    int nx = min(511, col + 15) - max(0, col - 15) + 1;
    if (col < 32) {
        int i = (col < 16) ? col : (512 + col);
        La[i] = 0.f; Lb[i] = 0.f;
    }
    for (int j = 0; j < 16; ++j) {
        int y = y0 + j;
        if (j > 0) {
            int ya = y + 15, yr = y - 16;
            if (ya < 512) {
                float4 q = rs4[pc + (size_t)ya * WW];
                sI += q.x; sP += q.y; sIP += q.z; sII += q.w;
            }
            if (yr >= 0) {
                float4 q = rs4[pc + (size_t)yr * WW];
                sI -= q.x; sP -= q.y; sIP -= q.z; sII -= q.w;
            }
        }
        int ny = min(511, y + 15) - max(0, y - 15) + 1;
        float N = (float)(ny * nx);
        float mI = sI / N, mP = sP / N, mIP = sIP / N, mII = sII / N;
        float cov = mIP - mI * mP;
        float var = mII - mI * mI;
        float a = cov / (var + 1e-3f);
        float bb = mP - a * mI;
        La[16 + col] = a;
        Lb[16 + col] = bb;
        __syncthreads();
        float sa = 0.f, sb = 0.f;
        #pragma unroll
        for (int k = -15; k <= 15; ++k) {
            sa += La[16 + col + k];
            sb += Lb[16 + col + k];
        }
        rab[pc + (size_t)y * WW] = make_float2(sa, sb);
        __syncthreads();
    }
}

// ============ final: running column sums of rab -> T, J, mapA (16-row segments) ============
__global__ void k_final_col(const float2* __restrict__ rab,
                            const float* __restrict__ Ib, const float* __restrict__ x,
                            const float* __restrict__ mapA3, float* __restrict__ out) {
    int bid = blockIdx.x;
    int b = bid >> 6, cg = (bid >> 5) & 1, seg = bid & 31;
    int col = cg * 256 + threadIdx.x;
    int y0 = seg * 16;
    size_t pc = (size_t)b * HW + col;
    float mA0 = mapA3[b * 3 + 0], mA1 = mapA3[b * 3 + 1], mA2 = mapA3[b * 3 + 2];
    const float* x0p = x + (size_t)b * 3 * HW + col;
    float Sa = 0.f, Sb = 0.f;
    for (int yy = y0 - 15; yy <= y0 + 15; ++yy) {
        if (yy >= 0 && yy < 512) {
            float2 q = rab[pc + (size_t)yy * WW];
            Sa += q.x; Sb += q.y;
        }
    }
    int nx = min(511, col + 15) - max(0, col - 15) + 1;
    for (int j = 0; j < 16; ++j) {
        int y = y0 + j;
        if (j > 0) {
            int ya = y + 15, yr = y - 16;
            if (ya < 512) {
                float2 q = rab[pc + (size_t)ya * WW];
                Sa += q.x; Sb += q.y;
            }
            if (yr >= 0) {
                float2 q = rab[pc + (size_t)yr * WW];
                Sa -= q.x; Sb -= q.y;
            }
        }
        int ny = min(511, y + 15) - max(0, y - 15) + 1;
        float N = (float)(ny * nx);
        float ma = Sa / N, mb = Sb / N;
        size_t yo = (size_t)y * WW;
        float Iv = Ib[pc + yo];
        float T = ma * Iv + mb;
        out[(size_t)3 * BHW + pc + yo] = T;
        float i0 = img01(x0p[yo]);
        float i1 = img01(x0p[(size_t)HW + yo]);
        float i2 = img01(x0p[(size_t)2 * HW + yo]);
        size_t j0 = (size_t)(b * 3) * HW + yo + col;
        out[j0] = (i0 - mA0) / T + mA0;
        out[j0 + HW] = (i1 - mA1) / T + mA1;
        out[j0 + 2 * HW] = (i2 - mA2) / T + mA2;
        out[(size_t)4 * BHW + j0] = mA0;
        out[(size_t)4 * BHW + j0 + HW] = mA1;
        out[(size_t)4 * BHW + j0 + 2 * HW] = mA2;
    }
}

extern "C" void kernel_launch(void* const* d_in, const int* in_sizes, int n_in,
                              void* d_out, int out_size, void* d_ws, size_t ws_size,
                              hipStream_t stream) {
    const float* x = (const float*)d_in[0];
    float* out = (float*)d_out;
    char* ws = (char*)d_ws;

    // ws layout: Ib [0,1)BHW | rm [1,2)BHW | dc [2,3)BHW | cand | mapA3
    float* Ib = (float*)ws;                    // guidance
    float* rm = Ib + (size_t)BHW;              // row-min (1st DC, then 2nd DC)
    float* dc = Ib + (size_t)2 * BHW;          // dark channel
    uint2* cand = (uint2*)(ws + (size_t)3 * BHW * 4);            // 16*4608 uint2 = 576 KB
    char* small = ws + (size_t)3 * BHW * 4 + (size_t)1024 * 1024;
    float* mapA3 = (float*)(small);
    // rs float4 AoS lives in d_out (64 MB; consumed by colab before final writes)
    float4* rs4 = (float4*)out;
    // rab float2 AoS overlays rm+dc (both dead by the time colab writes it): 32 MB
    float2* rab = (float2*)rm;

    // dark channel of imgPatch (bit-exact min path) + cand zero-init
    k_dc_row<<<16 * 512, 256, 0, stream>>>(x, Ib, rm, cand);
    k_dc_col0<<<16 * 4 * 8, 256, 0, stream>>>(rm, dc);

    // exact per-chunk top-262 (full-chip grid, register-resident)
    k_topkA<<<16 * 16, 256, 0, stream>>>(dc, cand);

    // dc2 rows with fused A-selection prologue (redundant+deterministic per block)
    k_dc2_row<<<16 * 32, 512, 0, stream>>>(x, cand, rm, mapA3);

    // trans_raw + GF row pass 1 (fused, float4 AoS out)
    k_trans_row1<<<16 * 32, 512, 0, stream>>>(rm, Ib, rs4);

    // GF col pass + a,b + row sums (fused, float2 AoS out), then final col pass + outputs
    k_colab_row2<<<16 * 32, 512, 0, stream>>>(rs4, rab);
    k_final_col<<<16 * 2 * 32, 256, 0, stream>>>(rab, Ib, x, mapA3, out);
}

// Round 18
// 254.707 us; speedup vs baseline: 1.1717x; 1.0358x over previous
//
#include <hip/hip_runtime.h>
#include <stdint.h>

#define BB 16
#define HH 512
#define WW 512
#define HW 262144            // 2^18
#define BHW 4194304          // 16 * 2^18
#define KSEL 262
#define CHK 16384            // phase-A chunk (16 per batch)
#define CSTRIDE 288          // per-chunk slots in cand (262 used + zero pad)
#define CBATCH (16 * CSTRIDE) // 4608 = 512*9 entries per batch

// ---------- helpers (rn intrinsics to suppress fma contraction in selection-critical math) ----------
__device__ __forceinline__ float img01(float xv) {
    return __fmul_rn(__fadd_rn(xv, 1.0f), 0.5f);
}
__device__ __forceinline__ float luma3(float c0, float c1, float c2) {
    float t = __fadd_rn(__fmul_rn(0.2989f, c0), __fmul_rn(0.587f, c1));
    return __fadd_rn(t, __fmul_rn(0.114f, c2));
}

// ---------- radix-16 exact k-th-largest select over register-resident values ----------
template <int ELT, int NW>
__device__ __forceinline__ void radix16_select(const uint32_t (&v)[ELT],
                                               unsigned long long* wsum, int t, int lane, int wv,
                                               uint32_t K, uint32_t& pref_out, uint32_t& r_out) {
    uint32_t pref = 0, target = K;
    for (int step = 0; step < 8; ++step) {
        int shift = 28 - 4 * step;
        uint32_t maskhi = step ? (0xFFFFFFFFu << (shift + 4)) : 0u;
        unsigned long long p0 = 0, p1 = 0, p2 = 0, p3 = 0;
        #pragma unroll
        for (int e = 0; e < ELT; ++e) {
            uint32_t u = v[e];
            bool ok = ((u & maskhi) == pref);
            uint32_t d = (u >> shift) & 15u;
            unsigned long long inc = ok ? (1ULL << ((d & 3u) * 16u)) : 0ULL;
            uint32_t q = d >> 2;
            p0 += (q == 0) ? inc : 0;
            p1 += (q == 1) ? inc : 0;
            p2 += (q == 2) ? inc : 0;
            p3 += (q == 3) ? inc : 0;
        }
        #pragma unroll
        for (int off = 32; off > 0; off >>= 1) {
            p0 += __shfl_down(p0, off, 64);
            p1 += __shfl_down(p1, off, 64);
            p2 += __shfl_down(p2, off, 64);
            p3 += __shfl_down(p3, off, 64);
        }
        if (lane == 0) {
            wsum[wv * 4 + 0] = p0; wsum[wv * 4 + 1] = p1;
            wsum[wv * 4 + 2] = p2; wsum[wv * 4 + 3] = p3;
        }
        __syncthreads();
        unsigned long long s0 = 0, s1 = 0, s2 = 0, s3 = 0;
        #pragma unroll
        for (int w = 0; w < NW; ++w) {
            s0 += wsum[w * 4 + 0]; s1 += wsum[w * 4 + 1];
            s2 += wsum[w * 4 + 2]; s3 += wsum[w * 4 + 3];
        }
        __syncthreads();
        uint32_t cum = 0, digit = 0, tgt = target;
        for (int d2 = 15; d2 >= 0; --d2) {
            unsigned long long ps = (d2 < 4) ? s0 : (d2 < 8) ? s1 : (d2 < 12) ? s2 : s3;
            uint32_t c2 = (uint32_t)((ps >> ((d2 & 3) * 16)) & 0xFFFFu);
            if (cum + c2 >= tgt) { digit = (uint32_t)d2; tgt -= cum; break; }
            cum += c2;
        }
        pref |= digit << shift;
        target = tgt;
    }
    pref_out = pref;
    r_out = target;
}

// ============ dark channel row pass (fused prep + cand zero-init) ============
__global__ void k_dc_row(const float* __restrict__ x, float* __restrict__ Ib, float* __restrict__ rm,
                         uint2* __restrict__ cand) {
    int bid = blockIdx.x;              // 16*512
    int b = bid >> 9, y = bid & 511;
    int t = threadIdx.x;
    if (bid < 16) {                    // zero one batch's cand region (incl. pads)
        unsigned long long* cz = (unsigned long long*)(cand + (size_t)bid * CBATCH);
        #pragma unroll
        for (int i = 0; i < 18; ++i) cz[i * 256 + t] = 0ull;   // 18*256 = 4608
    }
    __shared__ float lcm[528];         // logical [-8, 519], offset 8, pad = 1.0
    const float* xb = x + (size_t)b * 3 * HW + (size_t)y * WW;
    size_t obase = (size_t)b * HW + (size_t)y * WW;
    for (int xx = t; xx < 512; xx += 256) {
        float x0 = xb[xx], x1 = xb[HW + xx], x2 = xb[2 * HW + xx];
        float i0 = img01(x0), i1 = img01(x1), i2 = img01(x2);
        lcm[8 + xx] = fminf(i0, fminf(i1, i2));
        float tt = luma3(x0, x1, x2);
        Ib[obase + xx] = __fmul_rn(__fadd_rn(tt, 1.0f), 0.5f);
    }
    if (t < 16) lcm[(t < 8) ? t : (512 + t)] = 1.0f;
    __syncthreads();
    for (int xx = t; xx < 512; xx += 256) {
        float m = lcm[8 + xx - 7];
        #pragma unroll
        for (int k = -6; k <= 7; ++k) m = fminf(m, lcm[8 + xx + k]);
        rm[obase + xx] = m;
    }
}

// ============ col min pass (dark channel only): rm -> dc ============
__global__ void k_dc_col0(const float* __restrict__ in, float* __restrict__ out) {
    // grid 16*4*8; tile 128 cols x (64+14) rows
    int bid = blockIdx.x;
    int b = bid >> 5, cg = (bid >> 3) & 3, seg = bid & 7;
    int c0 = cg * 128, y0 = seg * 64;
    int t = threadIdx.x;
    __shared__ float tile[78 * 128];
    const float* ib = in + (size_t)b * HW;
    for (int i = t; i < 78 * 128; i += 256) {
        int rr = i >> 7, cc = i & 127;
        int gy = y0 - 7 + rr;
        tile[i] = (gy >= 0 && gy < 512) ? ib[(size_t)gy * WW + c0 + cc] : 1.0f;
    }
    __syncthreads();
    int col = t & 127;
    int rbase = (t >> 7) * 32;
    size_t obase = (size_t)b * HW + c0 + col;
    for (int rr = rbase; rr < rbase + 32; ++rr) {
        float m = tile[rr * 128 + col];
        #pragma unroll
        for (int k = 1; k < 15; ++k) m = fminf(m, tile[(rr + k) * 128 + col]);
        out[obase + (size_t)(y0 + rr) * WW] = m;
    }
}

// ============ phase A: per-chunk (16384) exact local top-262, registers, full-chip grid ============
__global__ __launch_bounds__(256, 1) void k_topkA(const float* __restrict__ dc, uint2* __restrict__ cand) {
    int b = blockIdx.x >> 4, blk = blockIdx.x & 15;   // grid 256
    int t = threadIdx.x, lane = t & 63, wv = t >> 6;
    __shared__ unsigned long long wsum[16];
    __shared__ uint32_t woffs[4];
    uint32_t v[64];
    const uint4* d4 = (const uint4*)(dc + (size_t)b * HW + (size_t)blk * CHK);
    #pragma unroll
    for (int it = 0; it < 16; ++it) {
        uint4 q = d4[t * 16 + it];
        v[it * 4 + 0] = q.x; v[it * 4 + 1] = q.y; v[it * 4 + 2] = q.z; v[it * 4 + 3] = q.w;
    }
    uint32_t pref, target;
    radix16_select<64, 4>(v, wsum, t, lane, wv, KSEL, pref, target);
    uint32_t cg = 0, ct = 0;
    #pragma unroll
    for (int e = 0; e < 64; ++e) {
        cg += (v[e] > pref) ? 1u : 0u;
        ct += (v[e] == pref) ? 1u : 0u;
    }
    uint32_t packed = (cg << 16) | ct;
    uint32_t scan = packed;
    #pragma unroll
    for (int off = 1; off < 64; off <<= 1) {
        uint32_t n = __shfl_up(scan, off, 64);
        if (lane >= off) scan += n;
    }
    if (lane == 63) woffs[wv] = scan;
    __syncthreads();
    uint32_t woff = 0;
    #pragma unroll
    for (int w = 0; w < 4; ++w) woff += (w < wv) ? woffs[w] : 0u;
    uint32_t total = woffs[0] + woffs[1] + woffs[2] + woffs[3];
    uint32_t G = total >> 16;            // strict-greater count (<= 261)
    uint32_t excl = woff + scan - packed;
    uint32_t gpos = excl >> 16, tpos = excl & 0xFFFFu;
    uint2* cb = cand + (size_t)(b * 16 + blk) * CSTRIDE;
    #pragma unroll
    for (int e = 0; e < 64; ++e) {
        uint32_t u = v[e];
        uint32_t idx = (uint32_t)(blk * CHK + t * 64 + e);
        if (u > pref) { cb[gpos] = make_uint2(u, idx); ++gpos; }
        else if (u == pref) { if (tpos < target) cb[G + tpos] = make_uint2(u, idx); ++tpos; }
    }
}

// ============ dc2 row pass with fused A-selection prologue (batch-staged 16-row LDS) ============
// grid 16*32, 512 threads (8 waves). 34 KB LDS -> 4 blocks/CU (R16 lesson: keep occupancy).
// Row loop: 1 barrier total (stage all 16 rows, then barrier-free window reads).
__global__ __launch_bounds__(512) void k_dc2_row(const float* __restrict__ x,
                                                 const uint2* __restrict__ cand,
                                                 float* __restrict__ rm, float* __restrict__ mapA3) {
    int bid = blockIdx.x;              // 16*32
    int b = bid >> 5, seg = bid & 31;
    int t = threadIdx.x, lane = t & 63, wv = t >> 6;   // 8 waves
    __shared__ unsigned long long wsum[32];
    __shared__ uint32_t woffs[8];
    __shared__ unsigned long long redg[8], redt[8];
    __shared__ float sInv[3];
    __shared__ float LCM[16 * 528];    // 33.8 KB: 16 rows, logical col [-8,519] offset 8, pad 1.0
    const uint2* cb = cand + (size_t)b * CBATCH;
    const float* xb = x + (size_t)b * 3 * HW;
    uint32_t v[9];
    #pragma unroll
    for (int e = 0; e < 9; ++e) v[e] = cb[t * 9 + e].x;
    uint32_t pref, target;
    radix16_select<9, 8>(v, wsum, t, lane, wv, KSEL, pref, target);
    unsigned long long bg = 0;
    uint32_t c = 0;
    #pragma unroll
    for (int e = 0; e < 9; ++e) {
        uint32_t u = v[e];
        if (u == pref) {
            ++c;
        } else if (u > pref) {
            uint32_t gidx = cb[t * 9 + e].y;
            float i0 = img01(xb[gidx]), i1 = img01(xb[HW + gidx]), i2 = img01(xb[2 * HW + gidx]);
            float inten = luma3(i0, i1, i2);
            unsigned long long pk =
                ((unsigned long long)__float_as_uint(inten) << 32) | (uint32_t)(0xFFFFFFFFu - gidx);
            if (pk > bg) bg = pk;
        }
    }
    uint32_t cs = c;
    #pragma unroll
    for (int off = 1; off < 64; off <<= 1) {
        uint32_t n = __shfl_up(cs, off, 64);
        if (lane >= off) cs += n;
    }
    if (lane == 63) woffs[wv] = cs;
    __syncthreads();
    uint32_t woff = 0;
    #pragma unroll
    for (int w = 0; w < 8; ++w) woff += (w < wv) ? woffs[w] : 0u;
    uint32_t pos = woff + cs - c;
    unsigned long long bt = 0;
    #pragma unroll
    for (int e = 0; e < 9; ++e) {
        if (v[e] == pref) {
            if (pos < target) {
                uint32_t gidx = cb[t * 9 + e].y;
                float i0 = img01(xb[gidx]), i1 = img01(xb[HW + gidx]), i2 = img01(xb[2 * HW + gidx]);
                float inten = luma3(i0, i1, i2);
                unsigned long long pk =
                    ((unsigned long long)__float_as_uint(inten) << 32) | (uint32_t)(0xFFFFFFFFu - gidx);
                if (pk > bt) bt = pk;
            }
            ++pos;
        }
    }
    #pragma unroll
    for (int off = 32; off > 0; off >>= 1) {
        unsigned long long og = __shfl_down(bg, off, 64);
        unsigned long long ot = __shfl_down(bt, off, 64);
        if (og > bg) bg = og;
        if (ot > bt) bt = ot;
    }
    if (lane == 0) { redg[wv] = bg; redt[wv] = bt; }
    __syncthreads();
    if (t == 0) {
        unsigned long long g = 0, tie = 0;
        #pragma unroll
        for (int w = 0; w < 8; ++w) {
            if (redg[w] > g) g = redg[w];
            if (redt[w] > tie) tie = redt[w];
        }
        unsigned long long fin = ((g >> 32) >= (tie >> 32)) ? g : tie;   // equal intensity -> gt wins
        if (g == 0ull) fin = tie;
        uint32_t rem = 0xFFFFFFFFu - (uint32_t)(fin & 0xFFFFFFFFull);
        for (int c2 = 0; c2 < 3; ++c2) {
            float A = img01(xb[(size_t)c2 * HW + rem]);
            float mA = __fsub_rn(__fmul_rn(A, 2.0f), 1.0f);
            float Ap = __fmul_rn(__fadd_rn(mA, 1.0f), 0.5f);
            sInv[c2] = 1.0f / Ap;
            if (seg == 0) mapA3[b * 3 + c2] = mA;
        }
    }
    // pads for all 16 rows (1.0): threads 0..255, one slot each
    if (t < 256) {
        int j = t >> 4, s = t & 15;
        LCM[j * 528 + ((s < 8) ? s : (512 + s))] = 1.0f;
    }
    __syncthreads();
    float inv0 = sInv[0], inv1 = sInv[1], inv2 = sInv[2];
    int col = t;
    int y0 = seg * 16;
    // stage all 16 cmin rows (no barriers inside)
    #pragma unroll
    for (int j = 0; j < 16; ++j) {
        size_t ro = (size_t)(y0 + j) * WW + col;
        float v0 = __fmul_rn(img01(xb[ro]), inv0);
        float v1 = __fmul_rn(img01(xb[HW + ro]), inv1);
        float v2 = __fmul_rn(img01(xb[2 * HW + ro]), inv2);
        LCM[j * 528 + 8 + col] = fminf(v0, fminf(v1, v2));
    }
    __syncthreads();
    // row-min(15) per row, barrier-free reads
    #pragma unroll
    for (int j = 0; j < 16; ++j) {
        float m = LCM[j * 528 + 8 + col - 7];
        #pragma unroll
        for (int k = -6; k <= 7; ++k) m = fminf(m, LCM[j * 528 + 8 + col + k]);
        rm[(size_t)b * HW + (size_t)(y0 + j) * WW + col] = m;
    }
}

// ============ fused: col-min(15) of rm -> trans_raw -> GF row sums (float4 AoS) ============
__global__ void k_trans_row1(const float* __restrict__ rm, const float* __restrict__ Ib,
                             float4* __restrict__ rs4) {
    int bid = blockIdx.x;              // 16*32
    int b = bid >> 5, seg = bid & 31;
    int y0 = seg * 16;
    int col = threadIdx.x;             // 512 threads, one per column
    __shared__ float LI[544], LP[544]; // logical [-16,527], offset 16, pad 0
    const float* rmp = rm + (size_t)b * HW;
    float rv[30];
    #pragma unroll
    for (int rix = 0; rix < 30; ++rix) {
        int gy = y0 - 7 + rix;
        rv[rix] = (gy >= 0 && gy < 512) ? rmp[(size_t)gy * WW + col] : 1e30f;
    }
    float pv[16];
    #pragma unroll
    for (int j = 0; j < 16; ++j) {
        float m = rv[j];
        #pragma unroll
        for (int k = 1; k < 15; ++k) m = fminf(m, rv[j + k]);
        int y = y0 + j;
        if (y < 7 || y > 504) m = fminf(m, 1.0f);   // window clipped -> pad 1.0 participates
        pv[j] = __fsub_rn(1.0f, __fmul_rn(0.95f, m));
    }
    if (col < 32) {
        int i = (col < 16) ? col : (512 + col);
        LI[i] = 0.f; LP[i] = 0.f;
    }
    const float* ibp = Ib + (size_t)b * HW;
    #pragma unroll
    for (int j = 0; j < 16; ++j) {
        int y = y0 + j;
        LI[16 + col] = ibp[(size_t)y * WW + col];
        LP[16 + col] = pv[j];
        __syncthreads();
        float sI = 0.f, sP = 0.f, sIP = 0.f, sII = 0.f;
        #pragma unroll
        for (int k = -15; k <= 15; ++k) {
            float iv = LI[16 + col + k], pp = LP[16 + col + k];
            sI += iv; sP += pp; sIP += iv * pp; sII += iv * iv;
        }
        rs4[(size_t)b * HW + (size_t)y * WW + col] = make_float4(sI, sP, sIP, sII);
        __syncthreads();
    }
}

// ============ fused: GF col running-sums (float4 AoS) -> a,b (LDS) -> row sums (float2 AoS) ============
__global__ void k_colab_row2(const float4* __restrict__ rs4, float2* __restrict__ rab) {
    int bid = blockIdx.x;              // 16*32
    int b = bid >> 5, seg = bid & 31;
    int y0 = seg * 16;
    int col = threadIdx.x;             // 512 threads
    __shared__ float La[544], Lb[544];
    size_t pc = (size_t)b * HW + col;
    float sI = 0.f, sP = 0.f, sIP = 0.f, sII = 0.f;
    for (int yy = y0 - 15; yy <= y0 + 15; ++yy) {
        if (yy >= 0 && yy < 512) {
            float4 q = rs4[pc + (size_t)yy * WW];
            sI += q.x; sP += q.y; sIP += q.z; sII += q.w;
        }
    }
    int nx = min(511, col + 15) - max(0, col - 15) + 1;
    if (col < 32) {
        int i = (col < 16) ? col : (512 + col);
        La[i] = 0.f; Lb[i] = 0.f;
    }
    for (int j = 0; j < 16; ++j) {
        int y = y0 + j;
        if (j > 0) {
            int ya = y + 15, yr = y - 16;
            if (ya < 512) {
                float4 q = rs4[pc + (size_t)ya * WW];
                sI += q.x; sP += q.y; sIP += q.z; sII += q.w;
            }
            if (yr >= 0) {
                float4 q = rs4[pc + (size_t)yr * WW];
                sI -= q.x; sP -= q.y; sIP -= q.z; sII -= q.w;
            }
        }
        int ny = min(511, y + 15) - max(0, y - 15) + 1;
        float N = (float)(ny * nx);
        float mI = sI / N, mP = sP / N, mIP = sIP / N, mII = sII / N;
        float cov = mIP - mI * mP;
        float var = mII - mI * mI;
        float a = cov / (var + 1e-3f);
        float bb = mP - a * mI;
        La[16 + col] = a;
        Lb[16 + col] = bb;
        __syncthreads();
        float sa = 0.f, sb = 0.f;
        #pragma unroll
        for (int k = -15; k <= 15; ++k) {
            sa += La[16 + col + k];
            sb += Lb[16 + col + k];
        }
        rab[pc + (size_t)y * WW] = make_float2(sa, sb);
        __syncthreads();
    }
}

// ============ final: running column sums of rab -> T, J, mapA; Iv recomputed from x ============
__global__ void k_final_col(const float2* __restrict__ rab,
                            const float* __restrict__ x,
                            const float* __restrict__ mapA3, float* __restrict__ out) {
    int bid = blockIdx.x;
    int b = bid >> 6, cg = (bid >> 5) & 1, seg = bid & 31;
    int col = cg * 256 + threadIdx.x;
    int y0 = seg * 16;
    size_t pc = (size_t)b * HW + col;
    float mA0 = mapA3[b * 3 + 0], mA1 = mapA3[b * 3 + 1], mA2 = mapA3[b * 3 + 2];
    const float* x0p = x + (size_t)b * 3 * HW + col;
    float Sa = 0.f, Sb = 0.f;
    for (int yy = y0 - 15; yy <= y0 + 15; ++yy) {
        if (yy >= 0 && yy < 512) {
            float2 q = rab[pc + (size_t)yy * WW];
            Sa += q.x; Sb += q.y;
        }
    }
    int nx = min(511, col + 15) - max(0, col - 15) + 1;
    for (int j = 0; j < 16; ++j) {
        int y = y0 + j;
        if (j > 0) {
            int ya = y + 15, yr = y - 16;
            if (ya < 512) {
                float2 q = rab[pc + (size_t)ya * WW];
                Sa += q.x; Sb += q.y;
            }
            if (yr >= 0) {
                float2 q = rab[pc + (size_t)yr * WW];
                Sa -= q.x; Sb -= q.y;
            }
        }
        int ny = min(511, y + 15) - max(0, y - 15) + 1;
        float N = (float)(ny * nx);
        float ma = Sa / N, mb = Sb / N;
        size_t yo = (size_t)y * WW;
        float x0 = x0p[yo];
        float x1 = x0p[(size_t)HW + yo];
        float x2 = x0p[(size_t)2 * HW + yo];
        // Iv: bit-identical recompute of Ib (same instruction sequence as k_dc_row)
        float tt = luma3(x0, x1, x2);
        float Iv = __fmul_rn(__fadd_rn(tt, 1.0f), 0.5f);
        float T = ma * Iv + mb;
        out[(size_t)3 * BHW + pc + yo] = T;
        float i0 = img01(x0), i1 = img01(x1), i2 = img01(x2);
        size_t j0 = (size_t)(b * 3) * HW + yo + col;
        out[j0] = (i0 - mA0) / T + mA0;
        out[j0 + HW] = (i1 - mA1) / T + mA1;
        out[j0 + 2 * HW] = (i2 - mA2) / T + mA2;
        out[(size_t)4 * BHW + j0] = mA0;
        out[(size_t)4 * BHW + j0 + HW] = mA1;
        out[(size_t)4 * BHW + j0 + 2 * HW] = mA2;
    }
}

extern "C" void kernel_launch(void* const* d_in, const int* in_sizes, int n_in,
                              void* d_out, int out_size, void* d_ws, size_t ws_size,
                              hipStream_t stream) {
    const float* x = (const float*)d_in[0];
    float* out = (float*)d_out;
    char* ws = (char*)d_ws;

    // ws layout: Ib [0,1)BHW | rm [1,2)BHW | dc [2,3)BHW | cand | mapA3
    float* Ib = (float*)ws;                    // guidance
    float* rm = Ib + (size_t)BHW;              // row-min (1st DC, then 2nd DC)
    float* dc = Ib + (size_t)2 * BHW;          // dark channel
    uint2* cand = (uint2*)(ws + (size_t)3 * BHW * 4);            // 16*4608 uint2 = 576 KB
    char* small = ws + (size_t)3 * BHW * 4 + (size_t)1024 * 1024;
    float* mapA3 = (float*)(small);
    // rs float4 AoS lives in d_out (64 MB; consumed by colab before final writes)
    float4* rs4 = (float4*)out;
    // rab float2 AoS overlays rm+dc (both dead by the time colab writes it): 32 MB
    float2* rab = (float2*)rm;

    // dark channel of imgPatch (bit-exact min path) + cand zero-init
    k_dc_row<<<16 * 512, 256, 0, stream>>>(x, Ib, rm, cand);
    k_dc_col0<<<16 * 4 * 8, 256, 0, stream>>>(rm, dc);

    // exact per-chunk top-262 (full-chip grid, register-resident)
    k_topkA<<<16 * 16, 256, 0, stream>>>(dc, cand);

    // dc2 rows with fused A-selection prologue (batch-staged LDS, 1-barrier row phase)
    k_dc2_row<<<16 * 32, 512, 0, stream>>>(x, cand, rm, mapA3);

    // trans_raw + GF row pass 1 (fused, float4 AoS out)
    k_trans_row1<<<16 * 32, 512, 0, stream>>>(rm, Ib, rs4);

    // GF col pass + a,b + row sums (fused, float2 AoS out), then final col pass + outputs
    k_colab_row2<<<16 * 32, 512, 0, stream>>>(rs4, rab);
    k_final_col<<<16 * 2 * 32, 256, 0, stream>>>(rab, x, mapA3, out);
}